// Round 7
// baseline (336.640 us; speedup 1.0000x reference)
//
#include <hip/hip_runtime.h>
#include <hip/hip_fp16.h>
#include <math.h>

// ws float layout (header only, 4160 floats = 16.6 KB):
//  [0] E_sum  [1] tr_gp  [2..17] m[16]  [18..33] cs[16]
//  [64..2112)   B[16][128]   (written by k_reduce)
//  [2112..4160) P2[16][128]  (written by k_finalize)
// Scratch lives in the d_out features_pooled region (dead until k_unpool,
// which runs last and overwrites all of it):
//  out0[0        .. 800000)   Ah[N][16] fp16 shadow of assignments (3.2 MB)
//  out0[800000   .. 825008)   csp[GA][16] cluster-size partials
//  out0[825008   .. 843440)   ep[GE][18] edge partials
//  out0[843440   .. +GB*2048) bp[GB][2048] B partials
// No atomics anywhere; nothing needs zero-init.

#define WS_ESUM 0
#define WS_TR   1
#define WS_M    2
#define WS_CS   18
#define WS_B    64
#define WS_P2   2112

#define OFF_AH  0
#define OFF_CSP 800000
#define OFF_EP  825008
#define OFF_BP  843440

// ---------------------------------------------------------------- k_assign
// Quad layout: 4 lanes per node, each lane covers 32 channels.
// Writes A (fp32), Ah (fp16 shadow), csp (per-block cs partial).
__global__ __launch_bounds__(256) void k_assign(
    const float* __restrict__ F, const float* __restrict__ W,
    const float* __restrict__ bias, float* __restrict__ A,
    __half* __restrict__ Ah, float* __restrict__ csp, int N) {
  __shared__ float Ws[2048];       // fc_w [16][128]
  __shared__ float csred[4][16];
  int t = threadIdx.x;
#pragma unroll
  for (int i = 0; i < 8; i++) Ws[t + 256 * i] = W[t + 256 * i];
  __syncthreads();

  int p = t & 3;               // quad part: channels p*32 .. p*32+31
  int nl = t >> 2;             // node slot (0..63)
  int n = blockIdx.x * 64 + nl;
  bool active = (n < N);

  float a[16];
#pragma unroll
  for (int k = 0; k < 16; k++) a[k] = 0.f;

  if (active) {
    const float4* f4 = (const float4*)(F + (size_t)n * 128 + p * 32);
#pragma unroll
    for (int i = 0; i < 8; i++) {
      float4 f = f4[i];
#pragma unroll
      for (int k = 0; k < 16; k++) {
        float4 w = *(const float4*)(&Ws[k * 128 + p * 32 + i * 4]);
        a[k] = fmaf(f.x, w.x, a[k]);
        a[k] = fmaf(f.y, w.y, a[k]);
        a[k] = fmaf(f.z, w.z, a[k]);
        a[k] = fmaf(f.w, w.w, a[k]);
      }
    }
  }

  // reduce partial dots over the quad (all lanes execute)
#pragma unroll
  for (int k = 0; k < 16; k++) {
    a[k] += __shfl_xor(a[k], 1, 64);
    a[k] += __shfl_xor(a[k], 2, 64);
  }

  // softmax (redundant in all 4 quad lanes)
#pragma unroll
  for (int k = 0; k < 16; k++) a[k] += bias[k];
  float mx = a[0];
#pragma unroll
  for (int k = 1; k < 16; k++) mx = fmaxf(mx, a[k]);
  float s = 0.f;
#pragma unroll
  for (int k = 0; k < 16; k++) { a[k] = __expf(a[k] - mx); s += a[k]; }
  float inv = 1.0f / s;
#pragma unroll
  for (int k = 0; k < 16; k++) a[k] *= inv;

  if (active) {
    float4 g = make_float4(a[p * 4 + 0], a[p * 4 + 1], a[p * 4 + 2], a[p * 4 + 3]);
    ((float4*)(A + (size_t)n * 16))[p] = g;
    if (p == 0) {
      __half2 hh[4];
      hh[0].x = __float2half_rn(a[0]); hh[0].y = __float2half_rn(a[1]);
      hh[1].x = __float2half_rn(a[2]); hh[1].y = __float2half_rn(a[3]);
      hh[2].x = __float2half_rn(a[4]); hh[2].y = __float2half_rn(a[5]);
      hh[3].x = __float2half_rn(a[6]); hh[3].y = __float2half_rn(a[7]);
      *(uint4*)(Ah + (size_t)n * 16) = *(uint4*)hh;
    } else if (p == 1) {
      __half2 hh[4];
      hh[0].x = __float2half_rn(a[8]);  hh[0].y = __float2half_rn(a[9]);
      hh[1].x = __float2half_rn(a[10]); hh[1].y = __float2half_rn(a[11]);
      hh[2].x = __float2half_rn(a[12]); hh[2].y = __float2half_rn(a[13]);
      hh[3].x = __float2half_rn(a[14]); hh[3].y = __float2half_rn(a[15]);
      *(uint4*)(Ah + (size_t)n * 16 + 8) = *(uint4*)hh;
    }
  }

  // cluster sizes: count each node once (quad lane 0)
  int lane = t & 63, wid = t >> 6;
#pragma unroll
  for (int k = 0; k < 16; k++) {
    float v = (active && p == 0) ? a[k] : 0.f;
    for (int off = 32; off; off >>= 1) v += __shfl_xor(v, off, 64);
    if (lane == 0) csred[wid][k] = v;
  }
  __syncthreads();
  if (t < 16)
    csp[(size_t)blockIdx.x * 16 + t] =
        csred[0][t] + csred[1][t] + csred[2][t] + csred[3][t];
}

// ---------------------------------------------------------------- k_edge
// fp16 gathers: Ah row = 32 B (fits per-XCD L2 entirely: 3.2 MB).
// Block partials of E_sum, tr, m[16].
union H2F4 { float4 f4; __half2 h2[4]; };

__global__ __launch_bounds__(256) void k_edge(
    const int* __restrict__ row, const int* __restrict__ col,
    const float* __restrict__ val, const __half* __restrict__ Ah,
    float* __restrict__ ep, int E) {
  float eS = 0.f, tr = 0.f;
  float m[16];
#pragma unroll
  for (int i = 0; i < 16; i++) m[i] = 0.f;

  int tid = blockIdx.x * 256 + threadIdx.x;
  int T = gridDim.x * 256;
  for (int e = tid; e < E; e += T) {
    int r = row[e], c = col[e];
    float v = val[e];
    const float4* pc = (const float4*)(Ah + (size_t)c * 16);
    const float4* pr = (const float4*)(Ah + (size_t)r * 16);
    H2F4 uc0, uc1, ur0, ur1;
    uc0.f4 = pc[0]; uc1.f4 = pc[1];
    ur0.f4 = pr[0]; ur1.f4 = pr[1];
    float cf[16], rf[16];
#pragma unroll
    for (int j = 0; j < 4; j++) {
      float2 f;
      f = __half22float2(uc0.h2[j]); cf[2 * j] = f.x; cf[2 * j + 1] = f.y;
      f = __half22float2(uc1.h2[j]); cf[8 + 2 * j] = f.x; cf[9 + 2 * j] = f.y;
      f = __half22float2(ur0.h2[j]); rf[2 * j] = f.x; rf[2 * j + 1] = f.y;
      f = __half22float2(ur1.h2[j]); rf[8 + 2 * j] = f.x; rf[9 + 2 * j] = f.y;
    }
    eS += v;
    float d = 0.f;
#pragma unroll
    for (int k = 0; k < 16; k++) {
      m[k] = fmaf(v, cf[k], m[k]);
      d = fmaf(rf[k], cf[k], d);
    }
    tr = fmaf(v, d, tr);
  }

  float vals[18];
  vals[0] = eS; vals[1] = tr;
#pragma unroll
  for (int i = 0; i < 16; i++) vals[2 + i] = m[i];
#pragma unroll
  for (int i = 0; i < 18; i++) {
    float v = vals[i];
    for (int off = 32; off; off >>= 1) v += __shfl_xor(v, off, 64);
    vals[i] = v;
  }
  __shared__ float red[4][18];
  int lane = threadIdx.x & 63, wid = threadIdx.x >> 6;
  if (lane == 0) {
#pragma unroll
    for (int i = 0; i < 18; i++) red[wid][i] = vals[i];
  }
  __syncthreads();
  if (threadIdx.x < 18)
    ep[(size_t)blockIdx.x * 18 + threadIdx.x] =
        red[0][threadIdx.x] + red[1][threadIdx.x] +
        red[2][threadIdx.x] + red[3][threadIdx.x];
}

// ---------------------------------------------------------------- k_nodeB
// Block partials of B[k,c] = sum_n A[n,k]*F[n,c].
// thread: q = t&31 (float4 column), sub = t>>5 (node slot 0..7);
// wave F loads = one contiguous 1 KB.
__global__ __launch_bounds__(256) void k_nodeB(
    const float* __restrict__ F, const float* __restrict__ A,
    float* __restrict__ bp, int N) {
  int t = threadIdx.x;
  int q = t & 31;
  int sub = t >> 5;

  float4 acc[16];
#pragma unroll
  for (int k = 0; k < 16; k++) acc[k] = make_float4(0.f, 0.f, 0.f, 0.f);

  const float4* F4 = (const float4*)F;
  const float4* A4 = (const float4*)A;
  int stride = gridDim.x * 8;
  for (int n = blockIdx.x * 8 + sub; n < N; n += stride) {
    float4 f  = F4[(size_t)n * 32 + q];
    float4 a0 = A4[(size_t)n * 4 + 0];
    float4 a1 = A4[(size_t)n * 4 + 1];
    float4 a2 = A4[(size_t)n * 4 + 2];
    float4 a3 = A4[(size_t)n * 4 + 3];
    float av[16] = {a0.x, a0.y, a0.z, a0.w, a1.x, a1.y, a1.z, a1.w,
                    a2.x, a2.y, a2.z, a2.w, a3.x, a3.y, a3.z, a3.w};
#pragma unroll
    for (int k = 0; k < 16; k++) {
      acc[k].x = fmaf(av[k], f.x, acc[k].x);
      acc[k].y = fmaf(av[k], f.y, acc[k].y);
      acc[k].z = fmaf(av[k], f.z, acc[k].z);
      acc[k].w = fmaf(av[k], f.w, acc[k].w);
    }
  }

  // combine the two node slots sharing q (lanes xor 32)
#pragma unroll
  for (int k = 0; k < 16; k++) {
    acc[k].x += __shfl_xor(acc[k].x, 32, 64);
    acc[k].y += __shfl_xor(acc[k].y, 32, 64);
    acc[k].z += __shfl_xor(acc[k].z, 32, 64);
    acc[k].w += __shfl_xor(acc[k].w, 32, 64);
  }

  __shared__ float red[4][2048];   // 32 KB
  int lane = t & 63, wid = t >> 6;
  if (lane < 32) {
#pragma unroll
    for (int k = 0; k < 16; k++)
      *(float4*)&red[wid][k * 128 + q * 4] = acc[k];
  }
  __syncthreads();
  float* myp = bp + (size_t)blockIdx.x * 2048;
#pragma unroll
  for (int qq = 0; qq < 2; qq++) {
    int base = t * 8 + qq * 4;
    float4 s0 = *(float4*)&red[0][base];
    float4 s1 = *(float4*)&red[1][base];
    float4 s2 = *(float4*)&red[2][base];
    float4 s3 = *(float4*)&red[3][base];
    *(float4*)&myp[base] = make_float4(s0.x + s1.x + s2.x + s3.x,
                                       s0.y + s1.y + s2.y + s3.y,
                                       s0.z + s1.z + s2.z + s3.z,
                                       s0.w + s1.w + s2.w + s3.w);
  }
}

// ---------------------------------------------------------------- k_reduce
// 34 blocks: 0..31 reduce B partials (64 cells each), 32 reduces edge
// scalars, 33 reduces cluster sizes. All reads coalesced.
__global__ __launch_bounds__(256) void k_reduce(
    const float* __restrict__ csp, const float* __restrict__ ep,
    const float* __restrict__ bp, float* __restrict__ ws,
    int GA, int GE, int GB) {
  __shared__ float L[256];
  int t = threadIdx.x;
  int b = blockIdx.x;
  if (b < 32) {
    int cell = b * 64 + (t & 63);
    int seg = t >> 6;
    float s = 0.f;
    for (int g = seg; g < GB; g += 4) s += bp[(size_t)g * 2048 + cell];
    L[t] = s;
    __syncthreads();
    if (t < 64)
      ws[WS_B + b * 64 + t] = L[t] + L[64 + t] + L[128 + t] + L[192 + t];
  } else if (b == 32) {
    int i = t % 18, s = t / 18;
    float v = 0.f;
    if (s < 14) {
      for (int g = s; g < GE; g += 14) v += ep[(size_t)g * 18 + i];
    }
    L[t] = v;
    __syncthreads();
    if (t < 18) {
      float tot = 0.f;
#pragma unroll
      for (int ss = 0; ss < 14; ss++) tot += L[ss * 18 + t];
      ws[t] = tot;                       // E_sum, tr, m[16]
    }
  } else {
    int i = t & 15, s = t >> 4;
    float v = 0.f;
    for (int g = s; g < GA; g += 16) v += csp[(size_t)g * 16 + i];
    L[t] = v;
    __syncthreads();
    if (t < 16) {
      float tot = 0.f;
#pragma unroll
      for (int ss = 0; ss < 16; ss++) tot += L[ss * 16 + t];
      ws[WS_CS + t] = tot;
    }
  }
}

// ---------------------------------------------------------------- k_finalize
__global__ __launch_bounds__(256) void k_finalize(
    float* __restrict__ ws, float* __restrict__ loss_out, int N) {
  __shared__ float invcs[16];
  int t = threadIdx.x;
  if (t < 16) invcs[t] = 1.0f / ws[WS_CS + t];
  __syncthreads();
  const float* B = ws + WS_B;
  float* P2 = ws + WS_P2;
  const float scale = 1.0507009873554805f;
  const float alpha = 1.6732632423543772f;
#pragma unroll
  for (int idx = t; idx < 2048; idx += 256) {
    int k = idx >> 7;
    float x = B[idx] * invcs[k];
    float s = (x > 0.f) ? scale * x : scale * alpha * expm1f(x);
    P2[idx] = s * invcs[k];
  }
  if (t == 0) {
    float Es = ws[WS_ESUM], tr = ws[WS_TR];
    float m2 = 0.f;
#pragma unroll
    for (int i = 0; i < 16; i++) m2 += ws[WS_M + i] * ws[WS_M + i];
    float spectral = -(tr - m2 / (2.0f * Es)) / (2.0f * Es);
    float coll = 0.f;
    float tgt = (float)N / 16.0f;
#pragma unroll
    for (int i = 0; i < 16; i++) coll += fabsf(ws[WS_CS + i] - tgt);
    coll = coll / (float)N * (4.0f / 3.0f / 2.0f);  // sk/(sk-1)/2, sk=4
    loss_out[0] = spectral + coll;
  }
}

// ---------------------------------------------------------------- k_unpool
// out[n,c] = sum_k A[n,k] * P2[k,c]   (runs LAST — overwrites scratch)
__global__ __launch_bounds__(256) void k_unpool(
    const float* __restrict__ A, const float* __restrict__ P2,
    float* __restrict__ out, int N) {
  __shared__ float Ps[2048];
  int t = threadIdx.x;
#pragma unroll
  for (int i = 0; i < 8; i++) Ps[t + 256 * i] = P2[t + 256 * i];
  __syncthreads();
  int c = t & 127;
  int half = t >> 7;
  int pairs = (N + 1) >> 1;
  for (int p = blockIdx.x; p < pairs; p += gridDim.x) {
    int n = p * 2 + half;
    if (n < N) {
      const float4* a4 = (const float4*)(A + (size_t)n * 16);
      float4 a0 = a4[0], a1 = a4[1], a2 = a4[2], a3 = a4[3];
      float s = a0.x * Ps[0 * 128 + c] + a0.y * Ps[1 * 128 + c]
              + a0.z * Ps[2 * 128 + c] + a0.w * Ps[3 * 128 + c]
              + a1.x * Ps[4 * 128 + c] + a1.y * Ps[5 * 128 + c]
              + a1.z * Ps[6 * 128 + c] + a1.w * Ps[7 * 128 + c]
              + a2.x * Ps[8 * 128 + c] + a2.y * Ps[9 * 128 + c]
              + a2.z * Ps[10 * 128 + c] + a2.w * Ps[11 * 128 + c]
              + a3.x * Ps[12 * 128 + c] + a3.y * Ps[13 * 128 + c]
              + a3.z * Ps[14 * 128 + c] + a3.w * Ps[15 * 128 + c];
      out[(size_t)n * 128 + c] = s;
    }
  }
}

// ----------------------------------------------------------------
extern "C" void kernel_launch(void* const* d_in, const int* in_sizes, int n_in,
                              void* d_out, int out_size, void* d_ws, size_t ws_size,
                              hipStream_t stream) {
  const float* F    = (const float*)d_in[0];  // [N,128]
  const int*   erow = (const int*)d_in[1];    // [E]
  const int*   ecol = (const int*)d_in[2];    // [E]
  const float* eval_= (const float*)d_in[3];  // [E]
  const float* W    = (const float*)d_in[4];  // [16,128]
  const float* bias = (const float*)d_in[5];  // [16]

  int N = in_sizes[0] / 128;
  int E = in_sizes[1];

  float* out0 = (float*)d_out;                 // features_pooled [N,128]
  float* A    = out0 + (size_t)N * 128;        // assignments [N,16]
  float* loss = A + (size_t)N * 16;            // scalar
  float* ws   = (float*)d_ws;

  int GA = (N + 63) / 64;                      // k_assign grid (1563)
  int GE = 1024;                               // k_edge grid
  int GB = 1024;                               // k_nodeB grid

  // scratch inside the (not-yet-written) features_pooled output region
  __half* Ah  = (__half*)(out0 + OFF_AH);      // [N][16] fp16, 3.2 MB
  float*  csp = out0 + OFF_CSP;                // [GA][16]
  float*  ep  = out0 + OFF_EP;                 // [GE][18]
  float*  bp  = out0 + OFF_BP;                 // [GB][2048]

  k_assign<<<GA, 256, 0, stream>>>(F, W, bias, A, Ah, csp, N);
  k_edge<<<GE, 256, 0, stream>>>(erow, ecol, eval_, Ah, ep, E);
  k_nodeB<<<GB, 256, 0, stream>>>(F, A, bp, N);
  k_reduce<<<34, 256, 0, stream>>>(csp, ep, bp, ws, GA, GE, GB);
  k_finalize<<<1, 256, 0, stream>>>(ws, loss, N);
  k_unpool<<<1024, 256, 0, stream>>>(A, ws + WS_P2, out0, N);
}

// Round 8
// 269.008 us; speedup vs baseline: 1.2514x; 1.2514x over previous
//
#include <hip/hip_runtime.h>
#include <hip/hip_fp16.h>
#include <math.h>

// ws float layout (header only):
//  [0] E_sum  [1] tr_gp  [2..17] m[16]  [18..33] cs[16]
//  [64..2112)   B[16][128]   (written by k_reduce)
//  [2112..4160) P2[16][128]  (written by k_finalize)
// Scratch lives in the d_out features_pooled region (dead until k_unpool,
// which runs last and overwrites all of it):
//  out0[0      .. 800000)  Ah[N][16] fp16 shadow of assignments (3.2 MB)
//  out0[800000 .. 825008)  csp[GA][16] cluster-size partials
//  out0[825008 .. 861872)  ep[GE][18]  edge partials (GE=2048)
//  out0[861872 .. +GB*2048) bp[GB][2048] B partials (GB=1024)
// No atomics anywhere; nothing needs zero-init.

#define WS_ESUM 0
#define WS_TR   1
#define WS_M    2
#define WS_CS   18
#define WS_B    64
#define WS_P2   2112

#define OFF_AH  0
#define OFF_CSP 800000
#define OFF_EP  825008
#define OFF_BP  861872

// ---------------------------------------------------------------- k_assign
// Quad layout: 4 lanes per node, each lane covers 32 channels.
__global__ __launch_bounds__(256) void k_assign(
    const float* __restrict__ F, const float* __restrict__ W,
    const float* __restrict__ bias, float* __restrict__ A,
    __half* __restrict__ Ah, float* __restrict__ csp, int N) {
  __shared__ float Ws[2048];       // fc_w [16][128]
  __shared__ float csred[4][16];
  int t = threadIdx.x;
#pragma unroll
  for (int i = 0; i < 8; i++) Ws[t + 256 * i] = W[t + 256 * i];
  __syncthreads();

  int p = t & 3;               // quad part: channels p*32 .. p*32+31
  int nl = t >> 2;             // node slot (0..63)
  int n = blockIdx.x * 64 + nl;
  bool active = (n < N);

  float a[16];
#pragma unroll
  for (int k = 0; k < 16; k++) a[k] = 0.f;

  if (active) {
    const float4* f4 = (const float4*)(F + (size_t)n * 128 + p * 32);
#pragma unroll
    for (int i = 0; i < 8; i++) {
      float4 f = f4[i];
#pragma unroll
      for (int k = 0; k < 16; k++) {
        float4 w = *(const float4*)(&Ws[k * 128 + p * 32 + i * 4]);
        a[k] = fmaf(f.x, w.x, a[k]);
        a[k] = fmaf(f.y, w.y, a[k]);
        a[k] = fmaf(f.z, w.z, a[k]);
        a[k] = fmaf(f.w, w.w, a[k]);
      }
    }
  }

#pragma unroll
  for (int k = 0; k < 16; k++) {
    a[k] += __shfl_xor(a[k], 1, 64);
    a[k] += __shfl_xor(a[k], 2, 64);
  }

#pragma unroll
  for (int k = 0; k < 16; k++) a[k] += bias[k];
  float mx = a[0];
#pragma unroll
  for (int k = 1; k < 16; k++) mx = fmaxf(mx, a[k]);
  float s = 0.f;
#pragma unroll
  for (int k = 0; k < 16; k++) { a[k] = __expf(a[k] - mx); s += a[k]; }
  float inv = 1.0f / s;
#pragma unroll
  for (int k = 0; k < 16; k++) a[k] *= inv;

  if (active) {
    float4 g = make_float4(a[p * 4 + 0], a[p * 4 + 1], a[p * 4 + 2], a[p * 4 + 3]);
    ((float4*)(A + (size_t)n * 16))[p] = g;
    if (p == 0) {
      __half2 hh[4];
      hh[0].x = __float2half_rn(a[0]); hh[0].y = __float2half_rn(a[1]);
      hh[1].x = __float2half_rn(a[2]); hh[1].y = __float2half_rn(a[3]);
      hh[2].x = __float2half_rn(a[4]); hh[2].y = __float2half_rn(a[5]);
      hh[3].x = __float2half_rn(a[6]); hh[3].y = __float2half_rn(a[7]);
      *(uint4*)(Ah + (size_t)n * 16) = *(uint4*)hh;
    } else if (p == 1) {
      __half2 hh[4];
      hh[0].x = __float2half_rn(a[8]);  hh[0].y = __float2half_rn(a[9]);
      hh[1].x = __float2half_rn(a[10]); hh[1].y = __float2half_rn(a[11]);
      hh[2].x = __float2half_rn(a[12]); hh[2].y = __float2half_rn(a[13]);
      hh[3].x = __float2half_rn(a[14]); hh[3].y = __float2half_rn(a[15]);
      *(uint4*)(Ah + (size_t)n * 16 + 8) = *(uint4*)hh;
    }
  }

  int lane = t & 63, wid = t >> 6;
#pragma unroll
  for (int k = 0; k < 16; k++) {
    float v = (active && p == 0) ? a[k] : 0.f;
    for (int off = 32; off; off >>= 1) v += __shfl_xor(v, off, 64);
    if (lane == 0) csred[wid][k] = v;
  }
  __syncthreads();
  if (t < 16)
    csp[(size_t)blockIdx.x * 16 + t] =
        csred[0][t] + csred[1][t] + csred[2][t] + csred[3][t];
}

// ---------------------------------------------------------------- k_edge
// fp16 gathers (Ah row = 32 B). 2-edge manual unroll for MLP.
union H2F4 { float4 f4; __half2 h2[4]; };

__device__ __forceinline__ void edge_body(
    const __half* __restrict__ Ah, int r, int c, float v,
    float& eS, float& tr, float* m) {
  const float4* pc = (const float4*)(Ah + (size_t)c * 16);
  const float4* pr = (const float4*)(Ah + (size_t)r * 16);
  H2F4 uc0, uc1, ur0, ur1;
  uc0.f4 = pc[0]; uc1.f4 = pc[1];
  ur0.f4 = pr[0]; ur1.f4 = pr[1];
  float cf[16], rf[16];
#pragma unroll
  for (int j = 0; j < 4; j++) {
    float2 f;
    f = __half22float2(uc0.h2[j]); cf[2 * j] = f.x; cf[2 * j + 1] = f.y;
    f = __half22float2(uc1.h2[j]); cf[8 + 2 * j] = f.x; cf[9 + 2 * j] = f.y;
    f = __half22float2(ur0.h2[j]); rf[2 * j] = f.x; rf[2 * j + 1] = f.y;
    f = __half22float2(ur1.h2[j]); rf[8 + 2 * j] = f.x; rf[9 + 2 * j] = f.y;
  }
  eS += v;
  float d = 0.f;
#pragma unroll
  for (int k = 0; k < 16; k++) {
    m[k] = fmaf(v, cf[k], m[k]);
    d = fmaf(rf[k], cf[k], d);
  }
  tr = fmaf(v, d, tr);
}

__global__ __launch_bounds__(256) void k_edge(
    const int* __restrict__ row, const int* __restrict__ col,
    const float* __restrict__ val, const __half* __restrict__ Ah,
    float* __restrict__ ep, int E) {
  float eS = 0.f, tr = 0.f;
  float m[16];
#pragma unroll
  for (int i = 0; i < 16; i++) m[i] = 0.f;

  int tid = blockIdx.x * 256 + threadIdx.x;
  int T = gridDim.x * 256;
  int e = tid;
  for (; e + T < E; e += 2 * T) {
    int r0 = row[e], c0 = col[e];
    int r1 = row[e + T], c1 = col[e + T];
    float v0 = val[e], v1 = val[e + T];
    edge_body(Ah, r0, c0, v0, eS, tr, m);
    edge_body(Ah, r1, c1, v1, eS, tr, m);
  }
  for (; e < E; e += T)
    edge_body(Ah, row[e], col[e], val[e], eS, tr, m);

  float vals[18];
  vals[0] = eS; vals[1] = tr;
#pragma unroll
  for (int i = 0; i < 16; i++) vals[2 + i] = m[i];
#pragma unroll
  for (int i = 0; i < 18; i++) {
    float v = vals[i];
    for (int off = 32; off; off >>= 1) v += __shfl_xor(v, off, 64);
    vals[i] = v;
  }
  __shared__ float red[4][18];
  int lane = threadIdx.x & 63, wid = threadIdx.x >> 6;
  if (lane == 0) {
#pragma unroll
    for (int i = 0; i < 18; i++) red[wid][i] = vals[i];
  }
  __syncthreads();
  if (threadIdx.x < 18)
    ep[(size_t)blockIdx.x * 18 + threadIdx.x] =
        red[0][threadIdx.x] + red[1][threadIdx.x] +
        red[2][threadIdx.x] + red[3][threadIdx.x];
}

// ---------------------------------------------------------------- k_nodeB
// Block partials of B[k,c]; wave F loads = one contiguous 1 KB.
__global__ __launch_bounds__(256) void k_nodeB(
    const float* __restrict__ F, const float* __restrict__ A,
    float* __restrict__ bp, int N) {
  int t = threadIdx.x;
  int q = t & 31;
  int sub = t >> 5;

  float4 acc[16];
#pragma unroll
  for (int k = 0; k < 16; k++) acc[k] = make_float4(0.f, 0.f, 0.f, 0.f);

  const float4* F4 = (const float4*)F;
  const float4* A4 = (const float4*)A;
  int stride = gridDim.x * 8;
  for (int n = blockIdx.x * 8 + sub; n < N; n += stride) {
    float4 f  = F4[(size_t)n * 32 + q];
    float4 a0 = A4[(size_t)n * 4 + 0];
    float4 a1 = A4[(size_t)n * 4 + 1];
    float4 a2 = A4[(size_t)n * 4 + 2];
    float4 a3 = A4[(size_t)n * 4 + 3];
    float av[16] = {a0.x, a0.y, a0.z, a0.w, a1.x, a1.y, a1.z, a1.w,
                    a2.x, a2.y, a2.z, a2.w, a3.x, a3.y, a3.z, a3.w};
#pragma unroll
    for (int k = 0; k < 16; k++) {
      acc[k].x = fmaf(av[k], f.x, acc[k].x);
      acc[k].y = fmaf(av[k], f.y, acc[k].y);
      acc[k].z = fmaf(av[k], f.z, acc[k].z);
      acc[k].w = fmaf(av[k], f.w, acc[k].w);
    }
  }

#pragma unroll
  for (int k = 0; k < 16; k++) {
    acc[k].x += __shfl_xor(acc[k].x, 32, 64);
    acc[k].y += __shfl_xor(acc[k].y, 32, 64);
    acc[k].z += __shfl_xor(acc[k].z, 32, 64);
    acc[k].w += __shfl_xor(acc[k].w, 32, 64);
  }

  __shared__ float red[4][2048];   // 32 KB
  int lane = t & 63, wid = t >> 6;
  if (lane < 32) {
#pragma unroll
    for (int k = 0; k < 16; k++)
      *(float4*)&red[wid][k * 128 + q * 4] = acc[k];
  }
  __syncthreads();
  float* myp = bp + (size_t)blockIdx.x * 2048;
#pragma unroll
  for (int qq = 0; qq < 2; qq++) {
    int base = t * 8 + qq * 4;
    float4 s0 = *(float4*)&red[0][base];
    float4 s1 = *(float4*)&red[1][base];
    float4 s2 = *(float4*)&red[2][base];
    float4 s3 = *(float4*)&red[3][base];
    *(float4*)&myp[base] = make_float4(s0.x + s1.x + s2.x + s3.x,
                                       s0.y + s1.y + s2.y + s3.y,
                                       s0.z + s1.z + s2.z + s3.z,
                                       s0.w + s1.w + s2.w + s3.w);
  }
}

// ---------------------------------------------------------------- k_reduce
// 258 blocks, ILP-unrolled.
//  b in [0,256): B cells [b*8, b*8+8), 32 segments, 4 accumulators.
//  b == 256: edge scalars, flat reads stride 252 (= 14*18, keeps i = t%18).
//  b == 257: cluster sizes, flat reads stride 256 (keeps i = t%16).
__global__ __launch_bounds__(256) void k_reduce(
    const float* __restrict__ csp, const float* __restrict__ ep,
    const float* __restrict__ bp, float* __restrict__ ws,
    int GA, int GE, int GB) {
  __shared__ float L[256];
  int t = threadIdx.x;
  int b = blockIdx.x;
  if (b < 256) {
    int cell = b * 8 + (t & 7);
    int seg = t >> 3;                      // 0..31
    float s0 = 0.f, s1 = 0.f, s2 = 0.f, s3 = 0.f;
    int g = seg;
    for (; g + 96 < GB; g += 128) {
      s0 += bp[(size_t)g * 2048 + cell];
      s1 += bp[(size_t)(g + 32) * 2048 + cell];
      s2 += bp[(size_t)(g + 64) * 2048 + cell];
      s3 += bp[(size_t)(g + 96) * 2048 + cell];
    }
    for (; g < GB; g += 32) s0 += bp[(size_t)g * 2048 + cell];
    L[t] = (s0 + s1) + (s2 + s3);
    __syncthreads();
    if (t < 8) {
      float tot = 0.f;
#pragma unroll
      for (int s = 0; s < 32; s++) tot += L[s * 8 + t];
      ws[WS_B + b * 8 + t] = tot;
    }
  } else if (b == 256) {
    int n = GE * 18;
    float s0 = 0.f, s1 = 0.f, s2 = 0.f, s3 = 0.f;
    if (t < 252) {
      int f = t;
      for (; f + 756 < n; f += 1008) {
        s0 += ep[f]; s1 += ep[f + 252]; s2 += ep[f + 504]; s3 += ep[f + 756];
      }
      for (; f < n; f += 252) s0 += ep[f];
    }
    L[t] = (s0 + s1) + (s2 + s3);
    __syncthreads();
    if (t < 18) {
      float tot = 0.f;
#pragma unroll
      for (int j = 0; j < 14; j++) tot += L[j * 18 + t];
      ws[t] = tot;                        // E_sum, tr, m[16]
    }
  } else {
    int n = GA * 16;
    float s0 = 0.f, s1 = 0.f, s2 = 0.f, s3 = 0.f;
    int f = t;
    for (; f + 768 < n; f += 1024) {
      s0 += csp[f]; s1 += csp[f + 256]; s2 += csp[f + 512]; s3 += csp[f + 768];
    }
    for (; f < n; f += 256) s0 += csp[f];
    L[t] = (s0 + s1) + (s2 + s3);
    __syncthreads();
    if (t < 16) {
      float tot = 0.f;
#pragma unroll
      for (int j = 0; j < 16; j++) tot += L[j * 16 + t];
      ws[WS_CS + t] = tot;
    }
  }
}

// ---------------------------------------------------------------- k_finalize
__global__ __launch_bounds__(256) void k_finalize(
    float* __restrict__ ws, float* __restrict__ loss_out, int N) {
  __shared__ float invcs[16];
  int t = threadIdx.x;
  if (t < 16) invcs[t] = 1.0f / ws[WS_CS + t];
  __syncthreads();
  const float* B = ws + WS_B;
  float* P2 = ws + WS_P2;
  const float scale = 1.0507009873554805f;
  const float alpha = 1.6732632423543772f;
#pragma unroll
  for (int idx = t; idx < 2048; idx += 256) {
    int k = idx >> 7;
    float x = B[idx] * invcs[k];
    float s = (x > 0.f) ? scale * x : scale * alpha * expm1f(x);
    P2[idx] = s * invcs[k];
  }
  if (t == 0) {
    float Es = ws[WS_ESUM], tr = ws[WS_TR];
    float m2 = 0.f;
#pragma unroll
    for (int i = 0; i < 16; i++) m2 += ws[WS_M + i] * ws[WS_M + i];
    float spectral = -(tr - m2 / (2.0f * Es)) / (2.0f * Es);
    float coll = 0.f;
    float tgt = (float)N / 16.0f;
#pragma unroll
    for (int i = 0; i < 16; i++) coll += fabsf(ws[WS_CS + i] - tgt);
    coll = coll / (float)N * (4.0f / 3.0f / 2.0f);  // sk/(sk-1)/2, sk=4
    loss_out[0] = spectral + coll;
  }
}

// ---------------------------------------------------------------- k_unpool
// out[n,c] = sum_k A[n,k] * P2[k,c]   (runs LAST — overwrites scratch)
__global__ __launch_bounds__(256) void k_unpool(
    const float* __restrict__ A, const float* __restrict__ P2,
    float* __restrict__ out, int N) {
  __shared__ float Ps[2048];
  int t = threadIdx.x;
#pragma unroll
  for (int i = 0; i < 8; i++) Ps[t + 256 * i] = P2[t + 256 * i];
  __syncthreads();
  int c = t & 127;
  int half = t >> 7;
  int pairs = (N + 1) >> 1;
  for (int p = blockIdx.x; p < pairs; p += gridDim.x) {
    int n = p * 2 + half;
    if (n < N) {
      const float4* a4 = (const float4*)(A + (size_t)n * 16);
      float4 a0 = a4[0], a1 = a4[1], a2 = a4[2], a3 = a4[3];
      float s = a0.x * Ps[0 * 128 + c] + a0.y * Ps[1 * 128 + c]
              + a0.z * Ps[2 * 128 + c] + a0.w * Ps[3 * 128 + c]
              + a1.x * Ps[4 * 128 + c] + a1.y * Ps[5 * 128 + c]
              + a1.z * Ps[6 * 128 + c] + a1.w * Ps[7 * 128 + c]
              + a2.x * Ps[8 * 128 + c] + a2.y * Ps[9 * 128 + c]
              + a2.z * Ps[10 * 128 + c] + a2.w * Ps[11 * 128 + c]
              + a3.x * Ps[12 * 128 + c] + a3.y * Ps[13 * 128 + c]
              + a3.z * Ps[14 * 128 + c] + a3.w * Ps[15 * 128 + c];
      out[(size_t)n * 128 + c] = s;
    }
  }
}

// ----------------------------------------------------------------
extern "C" void kernel_launch(void* const* d_in, const int* in_sizes, int n_in,
                              void* d_out, int out_size, void* d_ws, size_t ws_size,
                              hipStream_t stream) {
  const float* F    = (const float*)d_in[0];  // [N,128]
  const int*   erow = (const int*)d_in[1];    // [E]
  const int*   ecol = (const int*)d_in[2];    // [E]
  const float* eval_= (const float*)d_in[3];  // [E]
  const float* W    = (const float*)d_in[4];  // [16,128]
  const float* bias = (const float*)d_in[5];  // [16]

  int N = in_sizes[0] / 128;
  int E = in_sizes[1];

  float* out0 = (float*)d_out;                 // features_pooled [N,128]
  float* A    = out0 + (size_t)N * 128;        // assignments [N,16]
  float* loss = A + (size_t)N * 16;            // scalar
  float* ws   = (float*)d_ws;

  int GA = (N + 63) / 64;                      // k_assign grid (1563)
  int GE = 2048;                               // k_edge grid
  int GB = 1024;                               // k_nodeB grid

  // scratch inside the (not-yet-written) features_pooled output region
  __half* Ah  = (__half*)(out0 + OFF_AH);      // [N][16] fp16, 3.2 MB
  float*  csp = out0 + OFF_CSP;                // [GA][16]
  float*  ep  = out0 + OFF_EP;                 // [GE][18]
  float*  bp  = out0 + OFF_BP;                 // [GB][2048]

  k_assign<<<GA, 256, 0, stream>>>(F, W, bias, A, Ah, csp, N);
  k_edge<<<GE, 256, 0, stream>>>(erow, ecol, eval_, Ah, ep, E);
  k_nodeB<<<GB, 256, 0, stream>>>(F, A, bp, N);
  k_reduce<<<258, 256, 0, stream>>>(csp, ep, bp, ws, GA, GE, GB);
  k_finalize<<<1, 256, 0, stream>>>(ws, loss, N);
  k_unpool<<<1024, 256, 0, stream>>>(A, ws + WS_P2, out0, N);
}